// Round 1
// baseline (537.280 us; speedup 1.0000x reference)
//
#include <hip/hip_runtime.h>

#define NN 100000
#define NE 1600000
#define NM 10000

__device__ inline float4 ld4(const float* p) { return *(const float4*)p; }
__device__ inline void st4(float* p, float4 v) { *(float4*)p = v; }
__device__ inline float4 relu4(float4 v) {
  v.x = fmaxf(v.x, 0.f); v.y = fmaxf(v.y, 0.f);
  v.z = fmaxf(v.z, 0.f); v.w = fmaxf(v.w, 0.f);
  return v;
}

// ---------- degree / CSR build ----------
__global__ __launch_bounds__(256) void deg_count_k(const int* __restrict__ dst,
                                                   int* __restrict__ deg) {
  int e = blockIdx.x * 256 + threadIdx.x;
  if (e < NE) atomicAdd(&deg[dst[e]], 1);
}

__global__ __launch_bounds__(256) void make_inv_k(const int* __restrict__ deg,
                                                  float* __restrict__ inv) {
  int i = blockIdx.x * 256 + threadIdx.x;
  if (i < NN) inv[i] = 1.0f / fmaxf((float)deg[i], 1.0f);
}

__global__ __launch_bounds__(1024) void scan1_k(const int* __restrict__ deg,
                                                int* __restrict__ excl,
                                                int* __restrict__ bsum, int n) {
  __shared__ int lds[1024];
  int tid = threadIdx.x;
  int gid = blockIdx.x * 1024 + tid;
  int v = (gid < n) ? deg[gid] : 0;
  lds[tid] = v;
  __syncthreads();
  for (int off = 1; off < 1024; off <<= 1) {
    int t = (tid >= off) ? lds[tid - off] : 0;
    __syncthreads();
    lds[tid] += t;
    __syncthreads();
  }
  if (gid < n) excl[gid] = lds[tid] - v;   // block-local exclusive scan
  if (tid == 1023) bsum[blockIdx.x] = lds[1023];
}

__global__ void scan2_k(int* __restrict__ bsum, int nb) {
  if (threadIdx.x == 0 && blockIdx.x == 0) {
    int run = 0;
    for (int i = 0; i < nb; ++i) { int t = bsum[i]; bsum[i] = run; run += t; }
  }
}

__global__ __launch_bounds__(256) void scan3_k(int* __restrict__ excl,
                                               const int* __restrict__ bsum,
                                               int* __restrict__ cursor, int n) {
  int gid = blockIdx.x * 256 + threadIdx.x;
  if (gid < n) {
    int v = excl[gid] + bsum[gid >> 10];
    excl[gid] = v;
    cursor[gid] = v;
  }
}

__global__ __launch_bounds__(256) void csr_build_k(const int* __restrict__ src,
                                                   const int* __restrict__ dst,
                                                   int* __restrict__ cursor,
                                                   int* __restrict__ csr) {
  int e = blockIdx.x * 256 + threadIdx.x;
  if (e < NE) {
    int p = atomicAdd(&cursor[dst[e]], 1);
    csr[p] = src[e];
  }
}

// ---------- dense GEMM: Y[r][c] = sum_k X[r][k] * W[k][c], 128 output cols ----------
template<bool ACC, bool BIAS, bool RELU>
__global__ __launch_bounds__(256) void gemm128(const float* __restrict__ X, int ldx,
                                               const float* __restrict__ W,
                                               const float* __restrict__ bias,
                                               float* __restrict__ Y, int nrows) {
  __shared__ float Wlds[128 * 128];
  __shared__ float Xlds[16 * 128];
  const int tid = threadIdx.x;
  for (int i = tid; i < 128 * 128 / 4; i += 256)
    ((float4*)Wlds)[i] = ((const float4*)W)[i];
  const int cq = (tid & 31) * 4;   // column base (4 cols per thread)
  const int s = tid >> 5;          // row slot 0..7  (rows s and s+8)
  const int ngroups = (nrows + 15) >> 4;
  for (int g = blockIdx.x; g < ngroups; g += gridDim.x) {
    const int rbase = g << 4;
    __syncthreads();               // Xlds reuse (and W staged on first iter)
    for (int i = tid; i < 16 * 32; i += 256) {
      int r = i >> 5, k4 = (i & 31) << 2;
      int row = rbase + r;
      float4 v = (row < nrows) ? ld4(X + (size_t)row * ldx + k4)
                               : make_float4(0.f, 0.f, 0.f, 0.f);
      st4(Xlds + r * 128 + k4, v);
    }
    __syncthreads();
    float4 a0 = make_float4(0.f, 0.f, 0.f, 0.f);
    float4 a1 = make_float4(0.f, 0.f, 0.f, 0.f);
#pragma unroll 16
    for (int k = 0; k < 128; ++k) {
      float4 w = ld4(Wlds + k * 128 + cq);
      float x0 = Xlds[s * 128 + k];
      float x1 = Xlds[(s + 8) * 128 + k];
      a0.x = fmaf(x0, w.x, a0.x); a0.y = fmaf(x0, w.y, a0.y);
      a0.z = fmaf(x0, w.z, a0.z); a0.w = fmaf(x0, w.w, a0.w);
      a1.x = fmaf(x1, w.x, a1.x); a1.y = fmaf(x1, w.y, a1.y);
      a1.z = fmaf(x1, w.z, a1.z); a1.w = fmaf(x1, w.w, a1.w);
    }
    int r0 = rbase + s, r1 = r0 + 8;
    if (r0 < nrows) {
      float* y = Y + (size_t)r0 * 128 + cq;
      float4 o = a0;
      if (ACC) { float4 p = ld4(y); o.x += p.x; o.y += p.y; o.z += p.z; o.w += p.w; }
      if (BIAS) { float4 b = ld4(bias + cq); o.x += b.x; o.y += b.y; o.z += b.z; o.w += b.w; }
      if (RELU) o = relu4(o);
      st4(y, o);
    }
    if (r1 < nrows) {
      float* y = Y + (size_t)r1 * 128 + cq;
      float4 o = a1;
      if (ACC) { float4 p = ld4(y); o.x += p.x; o.y += p.y; o.z += p.z; o.w += p.w; }
      if (BIAS) { float4 b = ld4(bias + cq); o.x += b.x; o.y += b.y; o.z += b.z; o.w += b.w; }
      if (RELU) o = relu4(o);
      st4(y, o);
    }
  }
}

// ---------- CSR gather-aggregate: out[v] = post(inv[v] * sum_{s in N(v)} hw[s] + b) ----------
template<bool RELU>
__global__ __launch_bounds__(256) void gather_agg_k(const float* __restrict__ hw,
                                                    const int* __restrict__ csr,
                                                    const int* __restrict__ offs,
                                                    const int* __restrict__ degv,
                                                    const float* __restrict__ inv,
                                                    const float* __restrict__ bias,
                                                    float* __restrict__ out) {
  int v = blockIdx.x * 8 + (threadIdx.x >> 5);
  if (v >= NN) return;
  int lane = threadIdx.x & 31;
  int start = offs[v], cnt = degv[v];
  float4 acc = make_float4(0.f, 0.f, 0.f, 0.f);
  for (int i = 0; i < cnt; ++i) {
    int sv = csr[start + i];
    float4 x = ld4(hw + (size_t)sv * 128 + lane * 4);
    acc.x += x.x; acc.y += x.y; acc.z += x.z; acc.w += x.w;
  }
  float iv = inv[v];
  float4 b = ld4(bias + lane * 4);
  float4 o;
  o.x = fmaf(acc.x, iv, b.x); o.y = fmaf(acc.y, iv, b.y);
  o.z = fmaf(acc.z, iv, b.z); o.w = fmaf(acc.w, iv, b.w);
  if (RELU) o = relu4(o);
  st4(out + (size_t)v * 128 + lane * 4, o);
}

// ---------- layer-2 aggregate only at masked nodes, fused with relu + concat ----------
__global__ __launch_bounds__(256) void gather_masked_k(const float* __restrict__ hw2,
                                                       const float* __restrict__ feat,
                                                       const int* __restrict__ masked,
                                                       const int* __restrict__ csr,
                                                       const int* __restrict__ offs,
                                                       const int* __restrict__ degv,
                                                       const float* __restrict__ inv,
                                                       const float* __restrict__ b2,
                                                       float* __restrict__ xcat) {
  int m = blockIdx.x * 8 + (threadIdx.x >> 5);
  if (m >= NM) return;
  int lane = threadIdx.x & 31;
  int v = masked[m];
  int start = offs[v], cnt = degv[v];
  float4 acc = make_float4(0.f, 0.f, 0.f, 0.f);
  for (int i = 0; i < cnt; ++i) {
    int sv = csr[start + i];
    float4 x = ld4(hw2 + (size_t)sv * 128 + lane * 4);
    acc.x += x.x; acc.y += x.y; acc.z += x.z; acc.w += x.w;
  }
  float iv = inv[v];
  float4 b = ld4(b2 + lane * 4);
  float4 o;
  o.x = fmaf(acc.x, iv, b.x); o.y = fmaf(acc.y, iv, b.y);
  o.z = fmaf(acc.z, iv, b.z); o.w = fmaf(acc.w, iv, b.w);
  o = relu4(o);
  st4(xcat + (size_t)m * 256 + lane * 4, o);
  st4(xcat + (size_t)m * 256 + 128 + lane * 4, ld4(feat + (size_t)v * 128 + lane * 4));
}

extern "C" void kernel_launch(void* const* d_in, const int* in_sizes, int n_in,
                              void* d_out, int out_size, void* d_ws, size_t ws_size,
                              hipStream_t stream) {
  const float* feat = (const float*)d_in[0];
  const int* src = (const int*)d_in[1];
  const int* dst = (const int*)d_in[2];
  const int* masked = (const int*)d_in[3];
  const float* W1 = (const float*)d_in[4];
  const float* b1 = (const float*)d_in[5];
  const float* W2 = (const float*)d_in[6];
  const float* b2 = (const float*)d_in[7];
  const float* Wm1 = (const float*)d_in[8];
  const float* bm1 = (const float*)d_in[9];
  const float* Wm2 = (const float*)d_in[10];
  const float* bm2 = (const float*)d_in[11];
  const float* Wm3 = (const float*)d_in[12];
  float* out = (float*)d_out;

  // workspace layout
  int* deg = (int*)d_ws;                 // NN
  int* offs = deg + NN;                  // NN
  int* cursor = offs + NN;               // NN
  int* csr = cursor + NN;                // NE
  int* bsum = csr + NE;                  // 128
  float* inv = (float*)(bsum + 128);     // NN
  float* A = inv + NN;                   // NN*128  (16B-aligned by construction)
  float* B = A + (size_t)NN * 128;       // NN*128

  hipMemsetAsync(deg, 0, NN * sizeof(int), stream);
  deg_count_k<<<(NE + 255) / 256, 256, 0, stream>>>(dst, deg);
  make_inv_k<<<(NN + 255) / 256, 256, 0, stream>>>(deg, inv);
  int nb = (NN + 1023) / 1024;
  scan1_k<<<nb, 1024, 0, stream>>>(deg, offs, bsum, NN);
  scan2_k<<<1, 64, 0, stream>>>(bsum, nb);
  scan3_k<<<(NN + 255) / 256, 256, 0, stream>>>(offs, bsum, cursor, NN);
  csr_build_k<<<(NE + 255) / 256, 256, 0, stream>>>(src, dst, cursor, csr);

  // GCN layer 1: A = feat @ W1 ; B = relu(inv * agg(A) + b1)
  gemm128<false, false, false><<<512, 256, 0, stream>>>(feat, 128, W1, nullptr, A, NN);
  gather_agg_k<true><<<(NN + 7) / 8, 256, 0, stream>>>(A, csr, offs, deg, inv, b1, B);
  // GCN layer 2 (only masked dst needed): A = B @ W2 ; B[:, :256] = [relu(h2[mask]), feat[mask]]
  gemm128<false, false, false><<<512, 256, 0, stream>>>(B, 128, W2, nullptr, A, NN);
  gather_masked_k<<<(NM + 7) / 8, 256, 0, stream>>>(A, feat, masked, csr, offs, deg, inv, b2, B);

  // MLP head on M rows: split K=256 into two K=128 passes
  gemm128<false, false, false><<<512, 256, 0, stream>>>(B, 256, Wm1, nullptr, A, NM);
  gemm128<true, true, true><<<512, 256, 0, stream>>>(B + 128, 256, Wm1 + 128 * 128, bm1, A, NM);
  gemm128<false, true, true><<<512, 256, 0, stream>>>(A, 128, Wm2, bm2, B, NM);
  gemm128<false, false, false><<<512, 256, 0, stream>>>(B, 128, Wm3, nullptr, out, NM);
}